// Round 10
// baseline (172.100 us; speedup 1.0000x reference)
//
#include <hip/hip_runtime.h>

// BoundaryLoss, single-kernel full fusion at FULL CU coverage.
//
// x (8,4,256,256) f32; y (8,1,256,256) i32 in [0,4). out: scalar f32 mean.
// dist_map: +d(pos) at neg px, (1-d(neg)) at pos px, 0 if class absent.
// All squared distances are exact integers (<=130050): sqrtf + f32 mul + f64
// accumulation reproduces the np reference to ~1e-10 (absmax 0.0 measured).
//
// Key insight vs R6 (whole-plane LDS, 64 blocks, 65us): a 64-row output chunk
// needs only ITS rows' column-EDT, and that comes from a register-tracked scan
// of the full column (fwd to r0+63, bwd to r0; 320 iters) — no g workspace,
// no segment machinery. Grid 256 = 64 plane-masks x 4 chunks = all 256 CUs.
// Lessons kept: no __threadfence (R7: 52us hpass), no launch_bounds VGPR cap,
// int LDS tile with sentinel pre-mapped to BIG (R2), conditional x load (R4).

#define HH 256
#define WW 256
#define NPIX (HH*WW)
#define NPM 64              // 8 b * 4 k * 2 which
#define BIG (1 << 27)
#define NSTRIPE 64          // f64 stripes, 64B apart (4KB region + cnt)
#define RPB 64              // output rows per block
#define NBLK 256            // 64 pm * 4 row-chunks

__global__ void boundary_all(const int* __restrict__ y, const float* __restrict__ x,
                             double* __restrict__ acc, unsigned int* __restrict__ cnt,
                             float* __restrict__ out) {
    __shared__ int tile[RPB][WW];    // 64KB; col-EDT^2 of this block's rows
    __shared__ double wsum[4];
    __shared__ int lastFlag;

    int bid   = blockIdx.x;
    int pm    = bid >> 2;            // 0..63
    int rc    = bid & 3;             // row chunk
    int r0    = rc * RPB;
    int which = pm & 1;              // 0: feature=(y==k), 1: feature=(y!=k)
    int plane = pm >> 1;
    int b     = plane >> 2;
    int k     = plane & 3;
    int t     = threadIdx.x;         // = column

    const int*   yp = y + b * NPIX;
    const float* xp = x + (size_t)plane * NPIX;

    // ---- vertical, forward: rows 0 .. r0+RPB-1 (register-tracked) ----
    int last = -1000;
    int hEnd = r0 + RPB;
    for (int h = 0; h < hEnd; ++h) {
        int lab  = yp[h * WW + t];                  // coalesced 1KB/row, L2-hot
        int feat = ((lab == k) ? 1 : 0) ^ which;
        if (feat) last = h;
        if (h >= r0) tile[h - r0][t] = h - last;    // up-distance (<=1255)
    }
    // ---- vertical, backward: rows 255 .. r0; combine + square ----
    int nxt = 1000;
    for (int h = HH - 1; h >= r0; --h) {
        int lab  = yp[h * WW + t];
        int feat = ((lab == k) ? 1 : 0) ^ which;
        if (feat) nxt = h;
        if (h < hEnd) {
            int m = min(min(tile[h - r0][t], nxt - h), 256);
            tile[h - r0][t] = (m > 255) ? BIG : m * m;   // sentinel pre-mapped
        }
    }
    __syncthreads();

    // ---- horizontal batched-pruned exact search + fused contraction ----
    // min_j tile[i][j] + (t-j)^2; radii 4 at a time (8 LDS loads overlapped),
    // prune once per batch (lossless: |t-j|>=bs candidates >= bs^2 >= best).
    // Edge clamp to col 0/255 exact (clamped cand >= already-seen true cand).
    double lsum = 0.0;
    for (int i = 0; i < RPB; ++i) {
        int best = tile[i][t];
        #pragma unroll 1
        for (int bs = 1; bs < WW; bs += 4) {
            if (bs * bs >= best) break;
            int m = best;
            #pragma unroll
            for (int u = 0; u < 4; ++u) {
                int r  = bs + u;
                int rr = r * r;
                int jl = max(t - r, 0);
                int jr = min(t + r, WW - 1);
                m = min(m, tile[i][jl] + rr);
                m = min(m, tile[i][jr] + rr);
            }
            best = m;
        }
        // best==0: feature px (term 0). best>=BIG: class absent (has_pos).
        if (best > 0 && best < BIG) {
            float xv   = xp[(r0 + i) * WW + t];
            float dd   = sqrtf((float)best);           // exact-int sqrt
            float term = which ? (1.0f - dd) : dd;     // == -(d-1) exactly
            lsum += (double)(xv * term);               // f32 product, f64 acc
        }
    }

    // ---- block reduction: wave butterfly then 4 wave leaders ----
    for (int off = 32; off > 0; off >>= 1)
        lsum += __shfl_down(lsum, off, 64);
    int lane = t & 63, wv = t >> 6;
    if (lane == 0) wsum[wv] = lsum;
    __syncthreads();

    if (t == 0) {
        double s = wsum[0] + wsum[1] + wsum[2] + wsum[3];
        atomicAdd(&acc[(bid & (NSTRIPE - 1)) * 8], s);   // device-scope f64
        asm volatile("s_waitcnt vmcnt(0)" ::: "memory"); // ack before ticket
        unsigned int ticket = atomicAdd(cnt, 1u);
        lastFlag = (ticket == NBLK - 1) ? 1 : 0;
    }
    __syncthreads();

    // ---- last block: atomic reads serialize with stripe RMWs -> exact total
    if (lastFlag && t < 64) {
        double v = atomicAdd(&acc[t * 8], 0.0);
        for (int off = 32; off > 0; off >>= 1)
            v += __shfl_down(v, off, 64);
        if (t == 0) out[0] = (float)(v * (1.0 / 2097152.0));
    }
}

extern "C" void kernel_launch(void* const* d_in, const int* in_sizes, int n_in,
                              void* d_out, int out_size, void* d_ws, size_t ws_size,
                              hipStream_t stream) {
    const float* x = (const float*)d_in[0];
    const int*   y = (const int*)d_in[1];
    float* out = (float*)d_out;

    // ws layout: [0, 4096) 64 f64 stripes (stride 64B); [4096, 4100) u32 cnt
    double*       acc = (double*)d_ws;
    unsigned int* cnt = (unsigned int*)((char*)d_ws + 4096);

    hipMemsetAsync(d_ws, 0, 4104, stream);       // zero stripes + ticket
    boundary_all<<<NBLK, 256, 0, stream>>>(y, x, acc, cnt, out);
}

// Round 11
// 73.704 us; speedup vs baseline: 2.3350x; 2.3350x over previous
//
#include <hip/hip_runtime.h>

// BoundaryLoss: exact separable squared EDT per (b,k,which) plane-mask,
// fused with x*dist contraction. Three launches, measured-best pieces only.
//
// x (8,4,256,256) f32; y (8,1,256,256) i32 in [0,4). out: scalar f32 mean.
// dist_map: +d(pos) at neg px, (1-d(neg)) at pos px, 0 if class absent.
// All squared distances are exact integers (<=130050): sqrtf + f32 mul + f64
// accumulation reproduces the np reference to ~1e-10 (absmax 0.0 measured).
//
// Measured ledger:  R4 split 3-kernel = 78.9 total (floor ~53 + ours ~26).
//   R6 whole-plane fuse (16 w/CU, 64K px/CU) = 65us kernel.  R10 chunk fuse
//   (4 w/CU) = 115us kernel -> waves/CU controls latency-bound scans.
//   R7 vpass-1024 lb(256,4) ~= 3.5us (timeline subtraction) <- keep.
//   R7 hpass +threadfence +(256,8) VGPR=8 = 52us <- never do either.
//   R9 atomic tail in hpass = +5 vs separate finalize <- keep finalize split.

#define HH 256
#define WW 256
#define NPIX (HH*WW)
#define NPM 64              // 8 b * 4 k * 2 which
#define BIG (1 << 27)

// ---------------- Kernel 1: vertical pass (segmented column scan) ----------
// R7-measured config: 64 pm * 16 col-chunks = 1024 blocks, 256 thr, lb(256,4)
// -> 4 blk/CU, 16 waves/CU. thread = (seg 0..15) x (col 0..15), 16 rows each.
#define SEGS 16
#define RSEG 16
#define CPB 16

__global__ __launch_bounds__(256, 4) void edt_vpass(
        const int* __restrict__ y, unsigned short* __restrict__ g) {
    __shared__ unsigned short d[HH][CPB + 1];   // pad
    __shared__ short segLast[SEGS][CPB];        // last feature row (-1000 none)
    __shared__ short segFirst[SEGS][CPB];       // first feature row (1000 none)

    int bid   = blockIdx.x;
    int pm    = bid >> 4;               // 0..63
    int cc    = bid & 15;               // col chunk
    int which = pm & 1;                 // 0: feature=(y==k), 1: feature=(y!=k)
    int plane = pm >> 1;
    int b     = plane >> 2;
    int k     = plane & 3;

    int t   = threadIdx.x;
    int col = t & (CPB - 1);
    int seg = t >> 4;
    int w   = cc * CPB + col;
    int h0  = seg * RSEG;

    const int* yp = y + b * NPIX;
    unsigned short* gp = g + (size_t)pm * NPIX;

    // forward (downward) local scan
    int lastL = -1000, firstL = 1000;
    for (int i = 0; i < RSEG; ++i) {
        int h   = h0 + i;
        int lab = yp[h * WW + w];
        int feat = ((lab == k) ? 1 : 0) ^ which;
        if (feat) { lastL = h; if (firstL > 900) firstL = h; }
        d[h][col] = (unsigned short)min(h - lastL, 1000);
    }
    segLast[seg][col]  = (short)lastL;
    segFirst[seg][col] = (short)firstL;
    __syncthreads();

    // cross-segment prefix: nearest feature above / below my segment
    int prevLast = -1000;
    for (int s = seg - 1; s >= 0; --s) {
        int v = segLast[s][col];
        if (v >= 0) { prevLast = v; break; }
    }
    int nextFirst = 1000;
    for (int s = seg + 1; s < SEGS; ++s) {
        int v = segFirst[s][col];
        if (v < 900) { nextFirst = v; break; }
    }

    // backward scan + combine + square + store
    int nd = nextFirst;
    for (int i = RSEG - 1; i >= 0; --i) {
        int h  = h0 + i;
        int du = d[h][col];
        if (du == 0) nd = h;
        int dup = min(du, h - prevLast);
        int ddn = nd - h;
        int m   = min(min(dup, ddn), 256);
        gp[h * WW + w] = (m > 255) ? (unsigned short)0xFFFF
                                   : (unsigned short)(m * m);   // <= 65025
    }
}

// ---------------- Kernel 2: horizontal pass + fused contraction ------------
// 64 pm * 32 row-chunks = 2048 blocks, 256 thr, 8 rows -> 8KB tile,
// 8 blk/CU, 32 waves/CU. NO launch_bounds, NO fence, NO atomics.
// Batched pruned exact search: min_j g[j]+(w-j)^2, radii 4 at a time
// (8 LDS loads overlapped), prune per batch (lossless). Edge clamp exact.
#define ROWS_PER_BLK 8
#define NBLK2 2048

__global__ void edt_hpass(const unsigned short* __restrict__ g,
                          const float* __restrict__ x,
                          double* __restrict__ bsums) {
    __shared__ int tile[ROWS_PER_BLK][WW];   // sentinel pre-mapped to BIG
    __shared__ double wsum[4];

    int bid   = blockIdx.x;
    int pm    = bid >> 5;
    int rc    = bid & 31;
    int r0    = rc * ROWS_PER_BLK;
    int which = pm & 1;
    int plane = pm >> 1;
    int t     = threadIdx.x;   // = w

    const unsigned short* gp = g + (size_t)pm * NPIX;
    const float* xp = x + (size_t)plane * NPIX;

    // tile fill: uint loads (2 px); 8 rows * 128 uints = 1024 = 4*256
    const unsigned int* gp32 = (const unsigned int*)(gp + r0 * WW);
    #pragma unroll
    for (int i2 = 0; i2 < 4; ++i2) {
        int idx = i2 * 256 + t;
        int row = idx >> 7;
        int c2  = idx & 127;
        unsigned int v = gp32[row * 128 + c2];
        int v0 = (int)(v & 0xFFFFu);
        int v1 = (int)(v >> 16);
        tile[row][2 * c2]     = (v0 == 0xFFFF) ? BIG : v0;
        tile[row][2 * c2 + 1] = (v1 == 0xFFFF) ? BIG : v1;
    }
    __syncthreads();

    double lsum = 0.0;
    for (int i = 0; i < ROWS_PER_BLK; ++i) {
        int best = tile[i][t];
        #pragma unroll 1
        for (int bs = 1; bs < WW; bs += 4) {
            if (bs * bs >= best) break;          // lossless prune
            int m = best;
            #pragma unroll
            for (int u = 0; u < 4; ++u) {
                int r  = bs + u;
                int rr = r * r;
                int jl = max(t - r, 0);
                int jr = min(t + r, WW - 1);
                m = min(m, tile[i][jl] + rr);
                m = min(m, tile[i][jr] + rr);
            }
            best = m;
        }
        // best==0: feature px (term 0). best>=BIG: class absent (has_pos).
        if (best > 0 && best < BIG) {
            float xv   = xp[(r0 + i) * WW + t];        // conditional (R4 form)
            float dd   = sqrtf((float)best);           // exact-int sqrt
            float term = which ? (1.0f - dd) : dd;     // == -(d-1) exactly
            lsum += (double)(xv * term);               // f32 product, f64 acc
        }
    }

    // block reduction: wave butterfly then 4 wave leaders
    for (int off = 32; off > 0; off >>= 1)
        lsum += __shfl_down(lsum, off, 64);
    int lane = t & 63, wv = t >> 6;
    if (lane == 0) wsum[wv] = lsum;
    __syncthreads();
    if (t == 0) bsums[bid] = wsum[0] + wsum[1] + wsum[2] + wsum[3];
}

// ---------------- Kernel 3: final reduce + mean ----------------------------
__global__ void edt_finalize(const double* __restrict__ bsums, float* __restrict__ out) {
    __shared__ double wsum[4];
    int t = threadIdx.x;
    double s = 0.0;
    for (int i = t; i < NBLK2; i += 256) s += bsums[i];
    for (int off = 32; off > 0; off >>= 1)
        s += __shfl_down(s, off, 64);
    int lane = t & 63, wv = t >> 6;
    if (lane == 0) wsum[wv] = s;
    __syncthreads();
    if (t == 0)
        out[0] = (float)((wsum[0] + wsum[1] + wsum[2] + wsum[3]) * (1.0 / 2097152.0));
}

extern "C" void kernel_launch(void* const* d_in, const int* in_sizes, int n_in,
                              void* d_out, int out_size, void* d_ws, size_t ws_size,
                              hipStream_t stream) {
    const float* x = (const float*)d_in[0];
    const int*   y = (const int*)d_in[1];
    float* out = (float*)d_out;

    // ws layout: [0, 8MB) u16 g planes; [8MB, 8MB+16KB) f64 block sums
    unsigned short* g = (unsigned short*)d_ws;
    double* bsums = (double*)((char*)d_ws + (size_t)NPM * NPIX * sizeof(unsigned short));

    edt_vpass   <<<1024,  256, 0, stream>>>(y, g);
    edt_hpass   <<<NBLK2, 256, 0, stream>>>(g, x, bsums);
    edt_finalize<<<1,     256, 0, stream>>>(bsums, out);
}